// Round 5
// baseline (58.081 us; speedup 1.0000x reference)
//
#include <hip/hip_runtime.h>
#include <hip/hip_bf16.h>

#define N_TOTAL 8192
#define B_HALF  4096
#define D_DIM   256
#define BT      256                   // tile edge
#define NB2     32                    // 256-row blocks
#define NPAIRS  528                   // NB2*(NB2+1)/2 upper-triangle tiles
#define BK      64
#define NKT     (D_DIM / BK)          // 4 K-tiles

typedef __attribute__((ext_vector_type(8))) short  short8;   // 8 x bf16
typedef __attribute__((ext_vector_type(4))) float  f32x4;

// async global->LDS, 16B per lane (dest = wave-uniform base + lane*16)
#define GLOAD16(src, dst) __builtin_amdgcn_global_load_lds( \
    (const __attribute__((address_space(1))) unsigned int*)(src), \
    (__attribute__((address_space(3))) unsigned int*)(dst), 16, 0, 0)

// ---------------------------------------------------------------------------
// Kernel 1: fused normalize + positive-pair sim.  One WAVE per pair i.
// zn rows scaled by sqrt(2) so bf16 dot = 2*cos = s directly; pos in fp32.
// ---------------------------------------------------------------------------
__global__ __launch_bounds__(256) void nrmpos_kernel(const float* __restrict__ z1,
                                                     const float* __restrict__ z2,
                                                     __hip_bfloat16* __restrict__ zn,
                                                     float* __restrict__ pos) {
    int i    = (blockIdx.x * 256 + threadIdx.x) >> 6;   // pair 0..4095
    int lane = threadIdx.x & 63;
    float4 a = reinterpret_cast<const float4*>(z1 + (size_t)i * D_DIM)[lane];
    float4 b = reinterpret_cast<const float4*>(z2 + (size_t)i * D_DIM)[lane];
    float ssa = a.x * a.x + a.y * a.y + a.z * a.z + a.w * a.w;
    float ssb = b.x * b.x + b.y * b.y + b.z * b.z + b.w * b.w;
    float dab = a.x * b.x + a.y * b.y + a.z * b.z + a.w * b.w;
#pragma unroll
    for (int m = 32; m >= 1; m >>= 1) {
        ssa += __shfl_xor(ssa, m);
        ssb += __shfl_xor(ssb, m);
        dab += __shfl_xor(dab, m);
    }
    float inva = 1.0f / fmaxf(sqrtf(ssa), 1e-8f);
    float invb = 1.0f / fmaxf(sqrtf(ssb), 1e-8f);
    float sa = 1.4142135623730951f * inva;
    float sb = 1.4142135623730951f * invb;
    ushort4 oa, ob;
    { __hip_bfloat16 t = __float2bfloat16(a.x * sa); oa.x = *reinterpret_cast<unsigned short*>(&t); }
    { __hip_bfloat16 t = __float2bfloat16(a.y * sa); oa.y = *reinterpret_cast<unsigned short*>(&t); }
    { __hip_bfloat16 t = __float2bfloat16(a.z * sa); oa.z = *reinterpret_cast<unsigned short*>(&t); }
    { __hip_bfloat16 t = __float2bfloat16(a.w * sa); oa.w = *reinterpret_cast<unsigned short*>(&t); }
    { __hip_bfloat16 t = __float2bfloat16(b.x * sb); ob.x = *reinterpret_cast<unsigned short*>(&t); }
    { __hip_bfloat16 t = __float2bfloat16(b.y * sb); ob.y = *reinterpret_cast<unsigned short*>(&t); }
    { __hip_bfloat16 t = __float2bfloat16(b.z * sb); ob.z = *reinterpret_cast<unsigned short*>(&t); }
    { __hip_bfloat16 t = __float2bfloat16(b.w * sb); ob.w = *reinterpret_cast<unsigned short*>(&t); }
    reinterpret_cast<ushort4*>(zn + (size_t)i * D_DIM)[lane]            = oa;
    reinterpret_cast<ushort4*>(zn + (size_t)(i + B_HALF) * D_DIM)[lane] = ob;
    if (lane == 0) {
        float p = 2.0f * dab * inva * invb;
        pos[i]          = p;
        pos[i + B_HALF] = p;
    }
}

// ---------------------------------------------------------------------------
// Kernel 2: SYMMETRIC fused sim+exp, 256x256 tiles (128 FLOP/B staged — 2x
// round-4 intensity).  512 thr = 8 waves (2x4), wave = 128x64 out (8x4 frags).
// BK=64, dbuf LDS (128 KiB), proven stage->compute->syncthreads recipe.
//   rowacc -> partials[bj][bi*256 + r];  colacc -> partials[bi][bj*256 + c]
// Slot coverage per row-block R: {(R,bj):bj>=R} u {(bi,R):bi<R} = 32 slots
// exactly once -> no memset/atomics.
// Swizzle: LDS dest linear; source chunk ^= row&7; read-side XOR folds to
// lrow16&7 (even bank spread, same class as round-3's measured-0-conflict).
// ---------------------------------------------------------------------------
__global__ __launch_bounds__(512, 2) void simexp_kernel(const __hip_bfloat16* __restrict__ zn,
                                                        float* __restrict__ partials) {
    __shared__ __attribute__((aligned(16))) __hip_bfloat16 lA[2][BT * BK];
    __shared__ __attribute__((aligned(16))) __hip_bfloat16 lB[2][BT * BK];
    __shared__ float redr[8][128];
    __shared__ float redc[8][64];

    // --- triangular decode: id -> (bi,bj), C(b) = b*(65-b)/2 ---
    const int id = blockIdx.x;
    float ff = 32.5f - sqrtf(32.5f * 32.5f - 2.0f * (float)id);
    int bi = (int)ff;
    if (bi < 0) bi = 0;
    while ((bi + 1) * (65 - (bi + 1)) / 2 <= id) ++bi;
    while (bi * (65 - bi) / 2 > id) --bi;
    const int bj = bi + (id - bi * (65 - bi) / 2);
    const bool diag = (bi == bj);

    const int tid  = threadIdx.x;
    const int lane = tid & 63;
    const int wid  = tid >> 6;            // 0..7
    const int wr   = wid >> 2;            // wave row 0..1  (128 rows each)
    const int wc   = wid & 3;             // wave col 0..3  (64 cols each)
    const int lrow16 = lane & 15;
    const int kgrp   = lane >> 4;         // 0..3
    const int l7     = lrow16 & 7;        // read-side swizzle fold

    const __hip_bfloat16* Abase = zn + (size_t)bi * BT * D_DIM;
    const __hip_bfloat16* Bbase = zn + (size_t)bj * BT * D_DIM;

    // staging: tile = 256 rows x 64 elems = 2048 x 16B granules; 4 per thread.
    // slot g holds phys chunk g&7 of row g>>3; source logical chunk = (g&7)^(row&7)
    int gg[4], soff[4];
#pragma unroll
    for (int i = 0; i < 4; ++i) {
        gg[i] = tid + i * 512;
        const int r = gg[i] >> 3, c = gg[i] & 7;
        soff[i] = r * D_DIM + ((c ^ (r & 7)) * 8);
    }

    auto stage = [&](int t, int buf) {
        const int ko = t * BK;
#pragma unroll
        for (int i = 0; i < 4; ++i)
            GLOAD16(Abase + soff[i] + ko, &lA[buf][gg[i] * 8]);
#pragma unroll
        for (int i = 0; i < 4; ++i)
            GLOAD16(Bbase + soff[i] + ko, &lB[buf][gg[i] * 8]);
    };

    f32x4 acc[8][4];
#pragma unroll
    for (int mt = 0; mt < 8; ++mt)
#pragma unroll
        for (int nt = 0; nt < 4; ++nt) acc[mt][nt] = (f32x4)(0.0f);

    stage(0, 0);
    __syncthreads();

#pragma unroll
    for (int t = 0; t < NKT; ++t) {
        const int cur = t & 1;
        if (t + 1 < NKT) stage(t + 1, cur ^ 1);   // prefetch into other buf

#pragma unroll
        for (int ks = 0; ks < 2; ++ks) {          // BK=64 = 2 k-steps of 32
            const int pc = ((ks * 4 + kgrp) ^ l7) * 8;   // phys chunk elem-offset
            short8 af[8], bfr[4];
#pragma unroll
            for (int mt = 0; mt < 8; ++mt)
                af[mt] = *reinterpret_cast<const short8*>(
                    &lA[cur][(wr * 128 + mt * 16 + lrow16) * BK + pc]);
#pragma unroll
            for (int nt = 0; nt < 4; ++nt)
                bfr[nt] = *reinterpret_cast<const short8*>(
                    &lB[cur][(wc * 64 + nt * 16 + lrow16) * BK + pc]);
#pragma unroll
            for (int mt = 0; mt < 8; ++mt)
#pragma unroll
                for (int nt = 0; nt < 4; ++nt)
                    acc[mt][nt] = __builtin_amdgcn_mfma_f32_16x16x32_bf16(
                        af[mt], bfr[nt], acc[mt][nt], 0, 0, 0);
        }
        __syncthreads();                  // drains vmcnt: next buf staged & safe
    }

    // --- epilogue: e = exp(s-2); dual-axis accumulation ---
    float cs[4] = {0.0f, 0.0f, 0.0f, 0.0f};
#pragma unroll
    for (int mt = 0; mt < 8; ++mt) {
#pragma unroll
        for (int r = 0; r < 4; ++r) {
            float rsum = 0.0f;
            if (diag) {
                const int lrow = wr * 128 + mt * 16 + 4 * kgrp + r;
#pragma unroll
                for (int nt = 0; nt < 4; ++nt) {
                    const int lcol = wc * 64 + nt * 16 + lrow16;
                    float e = __expf(acc[mt][nt][r] - 2.0f);
                    rsum += (lrow == lcol) ? 0.0f : e;
                }
            } else {
#pragma unroll
                for (int nt = 0; nt < 4; ++nt) {
                    float e = __expf(acc[mt][nt][r] - 2.0f);
                    rsum += e;
                    cs[nt] += e;
                }
            }
            rsum += __shfl_xor(rsum, 1);
            rsum += __shfl_xor(rsum, 2);
            rsum += __shfl_xor(rsum, 4);
            rsum += __shfl_xor(rsum, 8);
            if (lrow16 == 0) redr[wid][mt * 16 + kgrp * 4 + r] = rsum;
        }
    }
    if (!diag) {
#pragma unroll
        for (int nt = 0; nt < 4; ++nt) {
            float c = cs[nt];
            c += __shfl_xor(c, 16);
            c += __shfl_xor(c, 32);
            if (kgrp == 0) redc[wid][nt * 16 + lrow16] = c;
        }
    }
    __syncthreads();

    if (tid < 256) {                       // row sums: 4 wave-cols combine
        const int r = tid;
        const int base = (r >> 7) * 4, l = r & 127;
        float s = redr[base][l] + redr[base + 1][l] + redr[base + 2][l] + redr[base + 3][l];
        partials[(size_t)bj * N_TOTAL + bi * BT + r] = s;
    } else if (!diag) {                    // col sums: 2 wave-rows combine
        const int c = tid - 256;
        const int wcc = c >> 6, l = c & 63;
        partials[(size_t)bi * N_TOTAL + bj * BT + c] = redc[wcc][l] + redc[4 + wcc][l];
    }
}

// ---------------------------------------------------------------------------
// Kernel 3: per-row lse - pos, block-partial sums (deterministic).
// ---------------------------------------------------------------------------
__global__ __launch_bounds__(256) void lse_kernel(const float* __restrict__ partials,
                                                  const float* __restrict__ pos,
                                                  float* __restrict__ bsums) {
    int tid = threadIdx.x;
    int row = blockIdx.x * 256 + tid;
    float s = 0.0f;
#pragma unroll 8
    for (int c = 0; c < NB2; ++c) s += partials[(size_t)c * N_TOTAL + row];
    float v = 2.0f + logf(s) - pos[row];
#pragma unroll
    for (int m = 32; m >= 1; m >>= 1) v += __shfl_xor(v, m);
    __shared__ float wsum[4];
    if ((tid & 63) == 0) wsum[tid >> 6] = v;
    __syncthreads();
    if (tid == 0) bsums[blockIdx.x] = wsum[0] + wsum[1] + wsum[2] + wsum[3];
}

__global__ void final_kernel(const float* __restrict__ bsums, float* __restrict__ out) {
    int tid = threadIdx.x;                // 64 threads
    float v = (tid < N_TOTAL / 256) ? bsums[tid] : 0.0f;
#pragma unroll
    for (int m = 32; m >= 1; m >>= 1) v += __shfl_xor(v, m);
    if (tid == 0) out[0] = v * (1.0f / (float)N_TOTAL);
}

// ---------------------------------------------------------------------------
extern "C" void kernel_launch(void* const* d_in, const int* in_sizes, int n_in,
                              void* d_out, int out_size, void* d_ws, size_t ws_size,
                              hipStream_t stream) {
    const float* z1 = (const float*)d_in[0];
    const float* z2 = (const float*)d_in[1];
    float* out = (float*)d_out;

    char* ws = (char*)d_ws;
    __hip_bfloat16* zn = (__hip_bfloat16*)ws;                              // 4 MB
    size_t off = (size_t)N_TOTAL * D_DIM * sizeof(__hip_bfloat16);
    float* pos = (float*)(ws + off);                                       // 32 KB
    off += (size_t)N_TOTAL * sizeof(float);
    float* partials = (float*)(ws + off);                                  // 1 MB
    off += (size_t)NB2 * N_TOTAL * sizeof(float);
    float* bsums = (float*)(ws + off);                                     // 128 B

    nrmpos_kernel<<<B_HALF / 4, 256, 0, stream>>>(z1, z2, zn, pos);
    simexp_kernel<<<NPAIRS, 512, 0, stream>>>(zn, partials);
    lse_kernel<<<N_TOTAL / 256, 256, 0, stream>>>(partials, pos, bsums);
    final_kernel<<<1, 64, 0, stream>>>(bsums, out);
}